// Round 13
// baseline (93.811 us; speedup 1.0000x reference)
//
#include <hip/hip_runtime.h>
#include <hip/hip_bf16.h>
#include <stdint.h>

#define BB    2
#define NRES  2048
#define TOPK  30
#define NRBF  16
#define NFEAT 416
#define NCH   128
#define NS8   108          // feat row stride in u32 (fp8): 432B = 16B-aligned
#define NKT   13           // k-steps of 32
#define RPB   2            // residues per block (edge kernel, M=64 GEMM)

typedef __attribute__((ext_vector_type(4))) float f32x4;
typedef unsigned long long u64;

// atoms record order: 0=N,1=Ca,2=Cb,3=C,4=O  (matches reference stack order)
__constant__ int c_pa[24] = {0,1,2,3,3,3,0,0,2,0,1,2,1,2,1,4,3,4,0,4,2,4,4,1};
__constant__ int c_pb[24] = {0,1,2,0,1,2,1,2,1,3,3,3,0,0,2,4,4,3,4,0,4,1,2,4};

static __device__ __forceinline__ unsigned pack4_fp8(float f0, float f1, float f2, float f3) {
  unsigned r = 0;
  r = __builtin_amdgcn_cvt_pk_fp8_f32(f0, f1, r, false);  // bytes 0,1
  r = __builtin_amdgcn_cvt_pk_fp8_f32(f2, f3, r, true);   // bytes 2,3
  return r;
}
static __device__ __forceinline__ u64 umin64(u64 a, u64 b) { return a < b ? a : b; }
static __device__ __forceinline__ u64 umax64(u64 a, u64 b) { return a > b ? a : b; }

// ---------------- kernel 1: prep = atoms records + Cpk + wB-fp8 (merged launch) -------
__global__ __launch_bounds__(256) void prep_kernel(const float* __restrict__ X,
                                                   const float* __restrict__ w_edge,
                                                   float* __restrict__ atoms,
                                                   float4* __restrict__ Cpk,
                                                   unsigned* __restrict__ wB8) {
  if (blockIdx.x < 16) {
    int id = blockIdx.x * 256 + threadIdx.x;
    const float* x = X + (size_t)id * 12;
    float nx = x[0], ny = x[1], nz = x[2];
    float cx = x[3], cy = x[4], cz = x[5];
    float ax = x[6], ay = x[7], az = x[8];
    float ox = x[9], oy = x[10], oz = x[11];
    float bx = ax - nx, by = ay - ny, bz = az - nz;
    float ccx = cx - ax, ccy = cy - ay, ccz = cz - az;
    float crx = by * ccz - bz * ccy;
    float cry = bz * ccx - bx * ccz;
    float crz = bx * ccy - by * ccx;
    float cbx = -0.58273431f * crx + 0.56802827f * bx - 0.54067466f * ccx + ax;
    float cby = -0.58273431f * cry + 0.56802827f * by - 0.54067466f * ccy + ay;
    float cbz = -0.58273431f * crz + 0.56802827f * bz - 0.54067466f * ccz + az;
    float* r = atoms + (size_t)id * 16;
    r[0] = nx;  r[1] = ny;  r[2] = nz;
    r[3] = ax;  r[4] = ay;  r[5] = az;
    r[6] = cbx; r[7] = cby; r[8] = cbz;
    r[9] = cx;  r[10] = cy; r[11] = cz;
    r[12] = ox; r[13] = oy; r[14] = oz;
    r[15] = 0.f;
    Cpk[id] = make_float4(cx, cy, cz, 0.f);
  } else {
    // byte wB8[((kt*8+nt)*64+lane)*8+j] = fp8(w_edge[(kt*32+(lane>>4)*8+j)*128 + nt*16+(lane&15)])
    int id = (blockIdx.x - 16) * 256 + threadIdx.x;  // u32 index
    if (id >= NFEAT * NCH / 4) return;
    int bb   = id * 4;
    int j0   = bb & 7;
    int lane = (bb >> 3) & 63;
    int nt   = (bb >> 9) & 7;
    int kt   = bb >> 12;
    int col  = nt * 16 + (lane & 15);
    int kb   = kt * 32 + ((lane >> 4) << 3) + j0;
    wB8[id] = pack4_fp8(w_edge[(size_t)(kb + 0) * NCH + col],
                        w_edge[(size_t)(kb + 1) * NCH + col],
                        w_edge[(size_t)(kb + 2) * NCH + col],
                        w_edge[(size_t)(kb + 3) * NCH + col]);
  }
}

// ---------------- kernel 2: top-30, ONE WAVE per residue, 2 winners per butterfly ----
// Keys unique ((d_bits<<32)|idx) -> strict ordering == jax tie-break. Verified round 9.
__global__ __launch_bounds__(256) void topk_kernel(const float4* __restrict__ Cpk,
                                                   int* __restrict__ eidx,
                                                   float* __restrict__ dn,
                                                   float* __restrict__ outI) {
  int tid = threadIdx.x;
  int lane = tid & 63;
  int bi = blockIdx.x * 4 + (tid >> 6);
  int b = bi >> 11;
  int i = bi & (NRES - 1);
  const float4* Cb = Cpk + (size_t)b * NRES;
  float4 ci = Cb[i];

  u64 key[4][8];
  u64 g1[4], g2[4];               // per-group smallest two
#pragma unroll
  for (int g = 0; g < 4; ++g) {
    g1[g] = ~0ull; g2[g] = ~0ull;
#pragma unroll
    for (int s = 0; s < 8; ++s) {
      int j = lane + 64 * (g * 8 + s);
      float4 cj = Cb[j];
      float dx = cj.x - ci.x, dy = cj.y - ci.y, dz = cj.z - ci.z;
      // match numpy op-for-op: ((dx*dx + dy*dy) + dz*dz) + 1e-6, no fma contraction
      float sm = __fadd_rn(__fadd_rn(__fadd_rn(__fmul_rn(dx, dx), __fmul_rn(dy, dy)),
                                     __fmul_rn(dz, dz)), 1e-6f);
      float d = sqrtf(sm);
      u64 kk = ((u64)__float_as_uint(d) << 32) | (unsigned)j;
      key[g][s] = kk;
      if (kk < g1[g]) { g2[g] = g1[g]; g1[g] = kk; }
      else if (kk < g2[g]) g2[g] = kk;
    }
  }

  for (int kk2 = 0; kk2 < TOPK / 2; ++kk2) {
    u64 x1 = umin64(g1[0], g1[1]);
    u64 x2 = umin64(umax64(g1[0], g1[1]), umin64(g2[0], g2[1]));
    u64 y1 = umin64(g1[2], g1[3]);
    u64 y2 = umin64(umax64(g1[2], g1[3]), umin64(g2[2], g2[3]));
    u64 m1 = umin64(x1, y1);
    u64 m2 = umin64(umax64(x1, y1), umin64(x2, y2));
#pragma unroll
    for (int off = 32; off; off >>= 1) {
      u64 o1 = __shfl_xor(m1, off, 64);
      u64 o2 = __shfl_xor(m2, off, 64);
      u64 n1 = umin64(m1, o1);
      u64 n2 = umin64(umax64(m1, o1), umin64(m2, o2));
      m1 = n1; m2 = n2;
    }
    if (lane == 0) {
      int i1 = (int)(unsigned)m1, i2 = (int)(unsigned)m2;
      size_t o = (size_t)bi * TOPK + 2 * kk2;
      eidx[o] = i1;           eidx[o + 1] = i2;
      dn[o]   = __uint_as_float((unsigned)(m1 >> 32));
      dn[o+1] = __uint_as_float((unsigned)(m2 >> 32));
      outI[o] = (float)i1;    outI[o + 1] = (float)i2;    // d_out is FLOAT32
    }
#pragma unroll
    for (int g = 0; g < 4; ++g) {
      bool hit = (g1[g] == m1) | (g1[g] == m2) | (g2[g] == m2);
      if (hit) {
        u64 n1 = ~0ull, n2 = ~0ull;
#pragma unroll
        for (int s = 0; s < 8; ++s) {
          u64 kv = key[g][s];
          if (kv == m1 || kv == m2) { kv = ~0ull; key[g][s] = kv; }
          if (kv < n1) { n2 = n1; n1 = kv; }
          else if (kv < n2) n2 = kv;
        }
        g1[g] = n1; g2[g] = n2;
      }
    }
  }
}

// ---------------- kernel 3: features (fp8) + M=64 MFMA fp8 GEMM + LayerNorm ----------
// 2 residues/block as one 64x416x128 GEMM. 256 threads = 4 waves; wave nq -> n-tiles
// {2nq,2nq+1} x 4 m-tiles (2 residues x 2 m-halves). B loads amortized over 8 MFMAs.
__global__ __launch_bounds__(256) void edge_mfma_kernel(
    const float* __restrict__ atoms, const int* __restrict__ eidx_g,
    const float* __restrict__ dn_g, const int* __restrict__ ridx,
    const int* __restrict__ chain, const float* __restrict__ w_pos,
    const float* __restrict__ b_pos, const unsigned* __restrict__ wB8,
    const float* __restrict__ gamma, const float* __restrict__ beta,
    float* __restrict__ outE) {
  __shared__ __align__(16) unsigned feat8[RPB * 32 * NS8];  // 27.6 KB fp8x4 features
  __shared__ float nat[RPB * TOPK][16];
  __shared__ float iat[RPB][16];
  __shared__ float dn_s[RPB * TOPK];
  __shared__ int   dsel[RPB * TOPK];
  __shared__ float2 lnp[RPB][32][4];          // per-residue per-row (sum,sumsq) per n-quarter

  int tid = threadIdx.x;
  int bi0 = blockIdx.x * RPB;                 // first residue of this block
  int b = bi0 >> 11;                          // no batch straddle (2048 % 2 == 0)
  int nq = tid >> 6, lane = tid & 63;
  int q = lane >> 4, ccol = lane & 15;

  // ---- phase A/B: edge lists + pos buckets + own atoms + neighbor gather + zero-pad ----
  if (tid < RPB * TOPK) {
    int gi = bi0 + tid / TOPK;
    int k = tid % TOPK;
    dn_s[tid] = dn_g[(size_t)gi * TOPK + k];
    int j = eidx_g[(size_t)gi * TOPK + k];
    int off = ridx[gi] - ridx[b * NRES + j];
    int ec = (chain[gi] == chain[b * NRES + j]) ? 1 : 0;
    int d = off + 32; d = d < 0 ? 0 : (d > 64 ? 64 : d);
    dsel[tid] = ec ? d : 65;
  }
  if (tid >= 64 && tid < 64 + RPB * 16) {
    int t = tid - 64;
    iat[t >> 4][t & 15] = atoms[((size_t)bi0 + (t >> 4)) * 16 + (t & 15)];
  }
  for (int idx = tid; idx < RPB * TOPK * 16; idx += 256) {
    int e = idx >> 4, f = idx & 15;
    int gi = bi0 + e / TOPK;
    nat[e][f] = atoms[((size_t)(b * NRES) + eidx_g[(size_t)gi * TOPK + (e % TOPK)]) * 16 + f];
  }
  for (int idx = tid; idx < RPB * 2 * NS8; idx += 256) {   // zero rows 30,31 both residues
    int r = idx / (2 * NS8), rem = idx % (2 * NS8);
    feat8[(r * 32 + 30) * NS8 + rem] = 0u;
  }
  __syncthreads();

  // ---- phase C: features (fp8x4 packed) ----
  if (tid < RPB * TOPK * 4) {                 // pos: 60 edges x 4 u32 (16 fp8)
    int e = tid >> 2, p = tid & 3;
    int f0 = p * 4, ds = dsel[e];
    int r = e / TOPK, k = e % TOPK;
    feat8[(r * 32 + k) * NS8 + p] = pack4_fp8(w_pos[ds * 16 + f0 + 0] + b_pos[f0 + 0],
                                              w_pos[ds * 16 + f0 + 1] + b_pos[f0 + 1],
                                              w_pos[ds * 16 + f0 + 2] + b_pos[f0 + 2],
                                              w_pos[ds * 16 + f0 + 3] + b_pos[f0 + 3]);
  }
  for (int idx = tid; idx < RPB * TOPK * 25; idx += 256) { // RBF: 60 edges x 25 groups
    int e = idx / 25, g = idx - e * 25;
    int r = e / TOPK, k = e - r * TOPK;
    float d;
    if (g == 0) {
      d = dn_s[e];
    } else {
      int qq = g - 1;
      const float* A  = &iat[r][c_pa[qq] * 3];
      const float* Bv = &nat[e][c_pb[qq] * 3];
      float dx = A[0] - Bv[0], dy = A[1] - Bv[1], dz = A[2] - Bv[2];
      d = sqrtf(dx * dx + dy * dy + dz * dz + 1e-6f);
    }
    float v[16];
#pragma unroll
    for (int j = 0; j < 16; ++j) {
      float mu = 2.0f + (float)j * (20.0f / 15.0f);  // linspace(2,22,16)
      float t = (d - mu) * 0.8f;                     // sigma = 1.25
      v[j] = __expf(-t * t);
    }
    uint4 w4 = make_uint4(pack4_fp8(v[0], v[1], v[2], v[3]),
                          pack4_fp8(v[4], v[5], v[6], v[7]),
                          pack4_fp8(v[8], v[9], v[10], v[11]),
                          pack4_fp8(v[12], v[13], v[14], v[15]));
    *(uint4*)&feat8[(r * 32 + k) * NS8 + 4 + 4 * g] = w4;   // 16B-aligned
  }
  __syncthreads();

  // ---- phase D: MFMA 16x16x32 fp8_fp8, M=64: 4 m-tiles share each B fragment ----
  const unsigned* ar00 = &feat8[(0 * 32 + ccol) * NS8];        // res 0, rows 0..15
  const unsigned* ar01 = &feat8[(0 * 32 + 16 + ccol) * NS8];   // res 0, rows 16..31
  const unsigned* ar10 = &feat8[(1 * 32 + ccol) * NS8];        // res 1, rows 0..15
  const unsigned* ar11 = &feat8[(1 * 32 + 16 + ccol) * NS8];   // res 1, rows 16..31
  const u64* wBll = (const u64*)wB8;

  f32x4 a000 = {}, a001 = {}, a010 = {}, a011 = {};   // res0: [mhalf][jn]
  f32x4 a100 = {}, a101 = {}, a110 = {}, a111 = {};   // res1: [mhalf][jn]
#pragma unroll
  for (int kt = 0; kt < NKT; ++kt) {
    union { unsigned u[2]; long long l; } f00, f01, f10, f11;
    int ao = kt * 8 + q * 2;
    f00.u[0] = ar00[ao]; f00.u[1] = ar00[ao + 1];     // ds_read_b64 x4
    f01.u[0] = ar01[ao]; f01.u[1] = ar01[ao + 1];
    f10.u[0] = ar10[ao]; f10.u[1] = ar10[ao + 1];
    f11.u[0] = ar11[ao]; f11.u[1] = ar11[ao + 1];
    long long b0 = (long long)wBll[(size_t)(kt * 8 + nq * 2 + 0) * 64 + lane];
    long long b1 = (long long)wBll[(size_t)(kt * 8 + nq * 2 + 1) * 64 + lane];
    a000 = __builtin_amdgcn_mfma_f32_16x16x32_fp8_fp8(f00.l, b0, a000, 0, 0, 0);
    a001 = __builtin_amdgcn_mfma_f32_16x16x32_fp8_fp8(f00.l, b1, a001, 0, 0, 0);
    a010 = __builtin_amdgcn_mfma_f32_16x16x32_fp8_fp8(f01.l, b0, a010, 0, 0, 0);
    a011 = __builtin_amdgcn_mfma_f32_16x16x32_fp8_fp8(f01.l, b1, a011, 0, 0, 0);
    a100 = __builtin_amdgcn_mfma_f32_16x16x32_fp8_fp8(f10.l, b0, a100, 0, 0, 0);
    a101 = __builtin_amdgcn_mfma_f32_16x16x32_fp8_fp8(f10.l, b1, a101, 0, 0, 0);
    a110 = __builtin_amdgcn_mfma_f32_16x16x32_fp8_fp8(f11.l, b0, a110, 0, 0, 0);
    a111 = __builtin_amdgcn_mfma_f32_16x16x32_fp8_fp8(f11.l, b1, a111, 0, 0, 0);
  }

  // ---- phase E: LayerNorm partials + store (both residues) ----
#pragma unroll
  for (int r = 0; r < RPB; ++r) {
#pragma unroll
    for (int mh = 0; mh < 2; ++mh) {
#pragma unroll
      for (int reg = 0; reg < 4; ++reg) {
        float v0, v1;
        if (r == 0) { v0 = mh ? a010[reg] : a000[reg]; v1 = mh ? a011[reg] : a001[reg]; }
        else        { v0 = mh ? a110[reg] : a100[reg]; v1 = mh ? a111[reg] : a101[reg]; }
        float s = v0 + v1, ss = v0 * v0 + v1 * v1;
        s  += __shfl_xor(s, 1, 64);  ss += __shfl_xor(ss, 1, 64);
        s  += __shfl_xor(s, 2, 64);  ss += __shfl_xor(ss, 2, 64);
        s  += __shfl_xor(s, 4, 64);  ss += __shfl_xor(ss, 4, 64);
        s  += __shfl_xor(s, 8, 64);  ss += __shfl_xor(ss, 8, 64);
        if (ccol == 0) lnp[r][(mh << 4) + q * 4 + reg][nq] = make_float2(s, ss);
      }
    }
  }
  __syncthreads();

  float g0 = gamma[(nq * 2 + 0) * 16 + ccol], be0 = beta[(nq * 2 + 0) * 16 + ccol];
  float g1 = gamma[(nq * 2 + 1) * 16 + ccol], be1 = beta[(nq * 2 + 1) * 16 + ccol];
#pragma unroll
  for (int r = 0; r < RPB; ++r) {
#pragma unroll
    for (int mh = 0; mh < 2; ++mh) {
#pragma unroll
      for (int reg = 0; reg < 4; ++reg) {
        int m = (mh << 4) + q * 4 + reg;
        if (m < TOPK) {
          float2 p0 = lnp[r][m][0], p1 = lnp[r][m][1], p2 = lnp[r][m][2], p3 = lnp[r][m][3];
          float s = (p0.x + p1.x) + (p2.x + p3.x);
          float ss = (p0.y + p1.y) + (p2.y + p3.y);
          float mu = s * (1.0f / 128.0f);
          float var = ss * (1.0f / 128.0f) - mu * mu;
          float rstd = rsqrtf(var + 1e-5f);
          float va, vb;
          if (r == 0) { va = mh ? a010[reg] : a000[reg]; vb = mh ? a011[reg] : a001[reg]; }
          else        { va = mh ? a110[reg] : a100[reg]; vb = mh ? a111[reg] : a101[reg]; }
          float* o = outE + ((size_t)(bi0 + r) * TOPK + m) * NCH + ccol;
          o[(nq * 2 + 0) * 16] = (va - mu) * rstd * g0 + be0;
          o[(nq * 2 + 1) * 16] = (vb - mu) * rstd * g1 + be1;
        }
      }
    }
  }
}

extern "C" void kernel_launch(void* const* d_in, const int* in_sizes, int n_in,
                              void* d_out, int out_size, void* d_ws, size_t ws_size,
                              hipStream_t stream) {
  const float* X      = (const float*)d_in[0];
  const int*   ridx   = (const int*)d_in[2];
  const int*   chain  = (const int*)d_in[3];
  const float* w_pos  = (const float*)d_in[4];
  const float* b_pos  = (const float*)d_in[5];
  const float* w_edge = (const float*)d_in[6];
  const float* gamma  = (const float*)d_in[7];
  const float* beta   = (const float*)d_in[8];

  float* outE = (float*)d_out;                         // output 0: E, float32
  float* outI = outE + (size_t)BB * NRES * TOPK * NCH; // output 1: E_idx as float32

  // workspace layout
  char* p = (char*)d_ws;
  float* atoms = (float*)p;                 p += (size_t)BB * NRES * 16 * 4;   // 256 KB
  int*   eidx  = (int*)p;                   p += (size_t)BB * NRES * TOPK * 4; // 480 KB
  float* dn    = (float*)p;                 p += (size_t)BB * NRES * TOPK * 4; // 480 KB
  unsigned* wB8 = (unsigned*)p;             p += (size_t)NCH * NFEAT;          // 52 KB
  float4* Cpk  = (float4*)p;                // 64 KB

  prep_kernel<<<16 + (NFEAT * NCH / 4 + 255) / 256, 256, 0, stream>>>(X, w_edge, atoms, Cpk, wB8);
  topk_kernel<<<BB * NRES / 4, 256, 0, stream>>>(Cpk, eidx, dn, outI);
  edge_mfma_kernel<<<BB * NRES / RPB, 256, 0, stream>>>(atoms, eidx, dn, ridx, chain,
                                                        w_pos, b_pos, wB8, gamma, beta, outE);
}

// Round 15
// 87.440 us; speedup vs baseline: 1.0729x; 1.0729x over previous
//
#include <hip/hip_runtime.h>
#include <hip/hip_bf16.h>
#include <stdint.h>

#define BB    2
#define NRES  2048
#define TOPK  30
#define NRBF  16
#define NFEAT 416
#define NCH   128
#define NS8   108          // feat row stride in u32 (fp8): 432B = 16B-aligned
#define NKT   13           // k-steps of 32
#define RPB   2            // residues per block (edge kernel, M=64 GEMM)

typedef __attribute__((ext_vector_type(4))) float f32x4;
typedef unsigned long long u64;

// atoms record order: 0=N,1=Ca,2=Cb,3=C,4=O  (matches reference stack order)
__constant__ int c_pa[24] = {0,1,2,3,3,3,0,0,2,0,1,2,1,2,1,4,3,4,0,4,2,4,4,1};
__constant__ int c_pb[24] = {0,1,2,0,1,2,1,2,1,3,3,3,0,0,2,4,4,3,4,0,4,1,2,4};

static __device__ __forceinline__ unsigned pack4_fp8(float f0, float f1, float f2, float f3) {
  unsigned r = 0;
  r = __builtin_amdgcn_cvt_pk_fp8_f32(f0, f1, r, false);  // bytes 0,1
  r = __builtin_amdgcn_cvt_pk_fp8_f32(f2, f3, r, true);   // bytes 2,3
  return r;
}

// ---------------- kernel 1: prep = atoms records + Cpk + wB-fp8 (merged launch) -------
__global__ __launch_bounds__(256) void prep_kernel(const float* __restrict__ X,
                                                   const float* __restrict__ w_edge,
                                                   float* __restrict__ atoms,
                                                   float4* __restrict__ Cpk,
                                                   unsigned* __restrict__ wB8) {
  if (blockIdx.x < 16) {
    int id = blockIdx.x * 256 + threadIdx.x;
    const float* x = X + (size_t)id * 12;
    float nx = x[0], ny = x[1], nz = x[2];
    float cx = x[3], cy = x[4], cz = x[5];
    float ax = x[6], ay = x[7], az = x[8];
    float ox = x[9], oy = x[10], oz = x[11];
    float bx = ax - nx, by = ay - ny, bz = az - nz;
    float ccx = cx - ax, ccy = cy - ay, ccz = cz - az;
    float crx = by * ccz - bz * ccy;
    float cry = bz * ccx - bx * ccz;
    float crz = bx * ccy - by * ccx;
    float cbx = -0.58273431f * crx + 0.56802827f * bx - 0.54067466f * ccx + ax;
    float cby = -0.58273431f * cry + 0.56802827f * by - 0.54067466f * ccy + ay;
    float cbz = -0.58273431f * crz + 0.56802827f * bz - 0.54067466f * ccz + az;
    float* r = atoms + (size_t)id * 16;
    r[0] = nx;  r[1] = ny;  r[2] = nz;
    r[3] = ax;  r[4] = ay;  r[5] = az;
    r[6] = cbx; r[7] = cby; r[8] = cbz;
    r[9] = cx;  r[10] = cy; r[11] = cz;
    r[12] = ox; r[13] = oy; r[14] = oz;
    r[15] = 0.f;
    Cpk[id] = make_float4(cx, cy, cz, 0.f);
  } else {
    // byte wB8[((kt*8+nt)*64+lane)*8+j] = fp8(w_edge[(kt*32+(lane>>4)*8+j)*128 + nt*16+(lane&15)])
    int id = (blockIdx.x - 16) * 256 + threadIdx.x;  // u32 index
    if (id >= NFEAT * NCH / 4) return;
    int bb   = id * 4;
    int j0   = bb & 7;
    int lane = (bb >> 3) & 63;
    int nt   = (bb >> 9) & 7;
    int kt   = bb >> 12;
    int col  = nt * 16 + (lane & 15);
    int kb   = kt * 32 + ((lane >> 4) << 3) + j0;
    wB8[id] = pack4_fp8(w_edge[(size_t)(kb + 0) * NCH + col],
                        w_edge[(size_t)(kb + 1) * NCH + col],
                        w_edge[(size_t)(kb + 2) * NCH + col],
                        w_edge[(size_t)(kb + 3) * NCH + col]);
  }
}

// ---------------- kernel 2: top-30, TWO residues per wave (interleaved ILP) ----------
// 256 threads = 4 waves = 8 residues/block. 1-winner subgrouped tournament (round-12
// algorithm, fastest measured); the two residues' serial shuffle chains overlap.
__global__ __launch_bounds__(256, 2) void topk_kernel(const float4* __restrict__ Cpk,
                                                      int* __restrict__ eidx,
                                                      float* __restrict__ dn,
                                                      float* __restrict__ outI) {
  int tid = threadIdx.x;
  int lane = tid & 63;
  int biA = blockIdx.x * 8 + (tid >> 6) * 2;    // wave handles biA, biA+1
  int biB = biA + 1;
  int b = biA >> 11;                             // same batch (8 | 2048)
  const float4* Cb = Cpk + (size_t)b * NRES;
  float4 ciA = Cb[biA & (NRES - 1)];
  float4 ciB = Cb[biB & (NRES - 1)];

  u64 keyA[4][8], keyB[4][8];
  u64 subA[4], subB[4];
#pragma unroll
  for (int g = 0; g < 4; ++g) {
    subA[g] = ~0ull; subB[g] = ~0ull;
#pragma unroll
    for (int s = 0; s < 8; ++s) {
      int j = lane + 64 * (g * 8 + s);
      float4 cj = Cb[j];                        // one load feeds both residues
      float dxA = cj.x - ciA.x, dyA = cj.y - ciA.y, dzA = cj.z - ciA.z;
      float dxB = cj.x - ciB.x, dyB = cj.y - ciB.y, dzB = cj.z - ciB.z;
      // match numpy op-for-op: ((dx*dx + dy*dy) + dz*dz) + 1e-6, no fma contraction
      float smA = __fadd_rn(__fadd_rn(__fadd_rn(__fmul_rn(dxA, dxA), __fmul_rn(dyA, dyA)),
                                      __fmul_rn(dzA, dzA)), 1e-6f);
      float smB = __fadd_rn(__fadd_rn(__fadd_rn(__fmul_rn(dxB, dxB), __fmul_rn(dyB, dyB)),
                                      __fmul_rn(dzB, dzB)), 1e-6f);
      float dA = sqrtf(smA), dB = sqrtf(smB);
      u64 kA = ((u64)__float_as_uint(dA) << 32) | (unsigned)j;
      u64 kB = ((u64)__float_as_uint(dB) << 32) | (unsigned)j;
      keyA[g][s] = kA; keyB[g][s] = kB;
      if (kA < subA[g]) subA[g] = kA;
      if (kB < subB[g]) subB[g] = kB;
    }
  }

  for (int k = 0; k < TOPK; ++k) {
    u64 a01 = subA[0] < subA[1] ? subA[0] : subA[1];
    u64 a23 = subA[2] < subA[3] ? subA[2] : subA[3];
    u64 gmA = a01 < a23 ? a01 : a23;
    u64 b01 = subB[0] < subB[1] ? subB[0] : subB[1];
    u64 b23 = subB[2] < subB[3] ? subB[2] : subB[3];
    u64 gmB = b01 < b23 ? b01 : b23;
#pragma unroll
    for (int off = 32; off; off >>= 1) {        // two independent butterflies, interleaved
      u64 oA = __shfl_xor(gmA, off, 64);
      u64 oB = __shfl_xor(gmB, off, 64);
      if (oA < gmA) gmA = oA;
      if (oB < gmB) gmB = oB;
    }
    if (lane == 0) {
      int iA = (int)(unsigned)(gmA & 0xffffffffu);
      int iB = (int)(unsigned)(gmB & 0xffffffffu);
      eidx[(size_t)biA * TOPK + k] = iA;
      eidx[(size_t)biB * TOPK + k] = iB;
      dn[(size_t)biA * TOPK + k] = __uint_as_float((unsigned)(gmA >> 32));
      dn[(size_t)biB * TOPK + k] = __uint_as_float((unsigned)(gmB >> 32));
      outI[(size_t)biA * TOPK + k] = (float)iA;  // d_out is FLOAT32
      outI[(size_t)biB * TOPK + k] = (float)iB;
    }
#pragma unroll
    for (int g = 0; g < 4; ++g) {               // owner subgroup: invalidate + re-min 8
      if (subA[g] == gmA) {
        subA[g] = ~0ull;
#pragma unroll
        for (int s = 0; s < 8; ++s) {
          if (keyA[g][s] == gmA) keyA[g][s] = ~0ull;
          if (keyA[g][s] < subA[g]) subA[g] = keyA[g][s];
        }
      }
      if (subB[g] == gmB) {
        subB[g] = ~0ull;
#pragma unroll
        for (int s = 0; s < 8; ++s) {
          if (keyB[g][s] == gmB) keyB[g][s] = ~0ull;
          if (keyB[g][s] < subB[g]) subB[g] = keyB[g][s];
        }
      }
    }
  }
}

// ---------------- kernel 3: features (fp8) + M=64 MFMA fp8 GEMM + LayerNorm ----------
// (unchanged from round 13: 2 residues/block, B loads amortized over 8 MFMAs)
__global__ __launch_bounds__(256) void edge_mfma_kernel(
    const float* __restrict__ atoms, const int* __restrict__ eidx_g,
    const float* __restrict__ dn_g, const int* __restrict__ ridx,
    const int* __restrict__ chain, const float* __restrict__ w_pos,
    const float* __restrict__ b_pos, const unsigned* __restrict__ wB8,
    const float* __restrict__ gamma, const float* __restrict__ beta,
    float* __restrict__ outE) {
  __shared__ __align__(16) unsigned feat8[RPB * 32 * NS8];  // 27.6 KB fp8x4 features
  __shared__ float nat[RPB * TOPK][16];
  __shared__ float iat[RPB][16];
  __shared__ float dn_s[RPB * TOPK];
  __shared__ int   dsel[RPB * TOPK];
  __shared__ float2 lnp[RPB][32][4];          // per-residue per-row (sum,sumsq) per n-quarter

  int tid = threadIdx.x;
  int bi0 = blockIdx.x * RPB;                 // first residue of this block
  int b = bi0 >> 11;                          // no batch straddle (2048 % 2 == 0)
  int nq = tid >> 6, lane = tid & 63;
  int q = lane >> 4, ccol = lane & 15;

  // ---- phase A/B: edge lists + pos buckets + own atoms + neighbor gather + zero-pad ----
  if (tid < RPB * TOPK) {
    int gi = bi0 + tid / TOPK;
    int k = tid % TOPK;
    dn_s[tid] = dn_g[(size_t)gi * TOPK + k];
    int j = eidx_g[(size_t)gi * TOPK + k];
    int off = ridx[gi] - ridx[b * NRES + j];
    int ec = (chain[gi] == chain[b * NRES + j]) ? 1 : 0;
    int d = off + 32; d = d < 0 ? 0 : (d > 64 ? 64 : d);
    dsel[tid] = ec ? d : 65;
  }
  if (tid >= 64 && tid < 64 + RPB * 16) {
    int t = tid - 64;
    iat[t >> 4][t & 15] = atoms[((size_t)bi0 + (t >> 4)) * 16 + (t & 15)];
  }
  for (int idx = tid; idx < RPB * TOPK * 16; idx += 256) {
    int e = idx >> 4, f = idx & 15;
    int gi = bi0 + e / TOPK;
    nat[e][f] = atoms[((size_t)(b * NRES) + eidx_g[(size_t)gi * TOPK + (e % TOPK)]) * 16 + f];
  }
  for (int idx = tid; idx < RPB * 2 * NS8; idx += 256) {   // zero rows 30,31 both residues
    int r = idx / (2 * NS8), rem = idx % (2 * NS8);
    feat8[(r * 32 + 30) * NS8 + rem] = 0u;
  }
  __syncthreads();

  // ---- phase C: features (fp8x4 packed) ----
  if (tid < RPB * TOPK * 4) {                 // pos: 60 edges x 4 u32 (16 fp8)
    int e = tid >> 2, p = tid & 3;
    int f0 = p * 4, ds = dsel[e];
    int r = e / TOPK, k = e % TOPK;
    feat8[(r * 32 + k) * NS8 + p] = pack4_fp8(w_pos[ds * 16 + f0 + 0] + b_pos[f0 + 0],
                                              w_pos[ds * 16 + f0 + 1] + b_pos[f0 + 1],
                                              w_pos[ds * 16 + f0 + 2] + b_pos[f0 + 2],
                                              w_pos[ds * 16 + f0 + 3] + b_pos[f0 + 3]);
  }
  for (int idx = tid; idx < RPB * TOPK * 25; idx += 256) { // RBF: 60 edges x 25 groups
    int e = idx / 25, g = idx - e * 25;
    int r = e / TOPK, k = e - r * TOPK;
    float d;
    if (g == 0) {
      d = dn_s[e];
    } else {
      int qq = g - 1;
      const float* A  = &iat[r][c_pa[qq] * 3];
      const float* Bv = &nat[e][c_pb[qq] * 3];
      float dx = A[0] - Bv[0], dy = A[1] - Bv[1], dz = A[2] - Bv[2];
      d = sqrtf(dx * dx + dy * dy + dz * dz + 1e-6f);
    }
    float v[16];
#pragma unroll
    for (int j = 0; j < 16; ++j) {
      float mu = 2.0f + (float)j * (20.0f / 15.0f);  // linspace(2,22,16)
      float t = (d - mu) * 0.8f;                     // sigma = 1.25
      v[j] = __expf(-t * t);
    }
    uint4 w4 = make_uint4(pack4_fp8(v[0], v[1], v[2], v[3]),
                          pack4_fp8(v[4], v[5], v[6], v[7]),
                          pack4_fp8(v[8], v[9], v[10], v[11]),
                          pack4_fp8(v[12], v[13], v[14], v[15]));
    *(uint4*)&feat8[(r * 32 + k) * NS8 + 4 + 4 * g] = w4;   // 16B-aligned
  }
  __syncthreads();

  // ---- phase D: MFMA 16x16x32 fp8_fp8, M=64: 4 m-tiles share each B fragment ----
  const unsigned* ar00 = &feat8[(0 * 32 + ccol) * NS8];        // res 0, rows 0..15
  const unsigned* ar01 = &feat8[(0 * 32 + 16 + ccol) * NS8];   // res 0, rows 16..31
  const unsigned* ar10 = &feat8[(1 * 32 + ccol) * NS8];        // res 1, rows 0..15
  const unsigned* ar11 = &feat8[(1 * 32 + 16 + ccol) * NS8];   // res 1, rows 16..31
  const u64* wBll = (const u64*)wB8;

  f32x4 a000 = {}, a001 = {}, a010 = {}, a011 = {};   // res0: [mhalf][jn]
  f32x4 a100 = {}, a101 = {}, a110 = {}, a111 = {};   // res1: [mhalf][jn]
#pragma unroll
  for (int kt = 0; kt < NKT; ++kt) {
    union { unsigned u[2]; long long l; } f00, f01, f10, f11;
    int ao = kt * 8 + q * 2;
    f00.u[0] = ar00[ao]; f00.u[1] = ar00[ao + 1];     // ds_read_b64 x4
    f01.u[0] = ar01[ao]; f01.u[1] = ar01[ao + 1];
    f10.u[0] = ar10[ao]; f10.u[1] = ar10[ao + 1];
    f11.u[0] = ar11[ao]; f11.u[1] = ar11[ao + 1];
    long long b0 = (long long)wBll[(size_t)(kt * 8 + nq * 2 + 0) * 64 + lane];
    long long b1 = (long long)wBll[(size_t)(kt * 8 + nq * 2 + 1) * 64 + lane];
    a000 = __builtin_amdgcn_mfma_f32_16x16x32_fp8_fp8(f00.l, b0, a000, 0, 0, 0);
    a001 = __builtin_amdgcn_mfma_f32_16x16x32_fp8_fp8(f00.l, b1, a001, 0, 0, 0);
    a010 = __builtin_amdgcn_mfma_f32_16x16x32_fp8_fp8(f01.l, b0, a010, 0, 0, 0);
    a011 = __builtin_amdgcn_mfma_f32_16x16x32_fp8_fp8(f01.l, b1, a011, 0, 0, 0);
    a100 = __builtin_amdgcn_mfma_f32_16x16x32_fp8_fp8(f10.l, b0, a100, 0, 0, 0);
    a101 = __builtin_amdgcn_mfma_f32_16x16x32_fp8_fp8(f10.l, b1, a101, 0, 0, 0);
    a110 = __builtin_amdgcn_mfma_f32_16x16x32_fp8_fp8(f11.l, b0, a110, 0, 0, 0);
    a111 = __builtin_amdgcn_mfma_f32_16x16x32_fp8_fp8(f11.l, b1, a111, 0, 0, 0);
  }

  // ---- phase E: LayerNorm partials + store (both residues) ----
#pragma unroll
  for (int r = 0; r < RPB; ++r) {
#pragma unroll
    for (int mh = 0; mh < 2; ++mh) {
#pragma unroll
      for (int reg = 0; reg < 4; ++reg) {
        float v0, v1;
        if (r == 0) { v0 = mh ? a010[reg] : a000[reg]; v1 = mh ? a011[reg] : a001[reg]; }
        else        { v0 = mh ? a110[reg] : a100[reg]; v1 = mh ? a111[reg] : a101[reg]; }
        float s = v0 + v1, ss = v0 * v0 + v1 * v1;
        s  += __shfl_xor(s, 1, 64);  ss += __shfl_xor(ss, 1, 64);
        s  += __shfl_xor(s, 2, 64);  ss += __shfl_xor(ss, 2, 64);
        s  += __shfl_xor(s, 4, 64);  ss += __shfl_xor(ss, 4, 64);
        s  += __shfl_xor(s, 8, 64);  ss += __shfl_xor(ss, 8, 64);
        if (ccol == 0) lnp[r][(mh << 4) + q * 4 + reg][nq] = make_float2(s, ss);
      }
    }
  }
  __syncthreads();

  float g0 = gamma[(nq * 2 + 0) * 16 + ccol], be0 = beta[(nq * 2 + 0) * 16 + ccol];
  float g1 = gamma[(nq * 2 + 1) * 16 + ccol], be1 = beta[(nq * 2 + 1) * 16 + ccol];
#pragma unroll
  for (int r = 0; r < RPB; ++r) {
#pragma unroll
    for (int mh = 0; mh < 2; ++mh) {
#pragma unroll
      for (int reg = 0; reg < 4; ++reg) {
        int m = (mh << 4) + q * 4 + reg;
        if (m < TOPK) {
          float2 p0 = lnp[r][m][0], p1 = lnp[r][m][1], p2 = lnp[r][m][2], p3 = lnp[r][m][3];
          float s = (p0.x + p1.x) + (p2.x + p3.x);
          float ss = (p0.y + p1.y) + (p2.y + p3.y);
          float mu = s * (1.0f / 128.0f);
          float var = ss * (1.0f / 128.0f) - mu * mu;
          float rstd = rsqrtf(var + 1e-5f);
          float va, vb;
          if (r == 0) { va = mh ? a010[reg] : a000[reg]; vb = mh ? a011[reg] : a001[reg]; }
          else        { va = mh ? a110[reg] : a100[reg]; vb = mh ? a111[reg] : a101[reg]; }
          float* o = outE + ((size_t)(bi0 + r) * TOPK + m) * NCH + ccol;
          o[(nq * 2 + 0) * 16] = (va - mu) * rstd * g0 + be0;
          o[(nq * 2 + 1) * 16] = (vb - mu) * rstd * g1 + be1;
        }
      }
    }
  }
}

extern "C" void kernel_launch(void* const* d_in, const int* in_sizes, int n_in,
                              void* d_out, int out_size, void* d_ws, size_t ws_size,
                              hipStream_t stream) {
  const float* X      = (const float*)d_in[0];
  const int*   ridx   = (const int*)d_in[2];
  const int*   chain  = (const int*)d_in[3];
  const float* w_pos  = (const float*)d_in[4];
  const float* b_pos  = (const float*)d_in[5];
  const float* w_edge = (const float*)d_in[6];
  const float* gamma  = (const float*)d_in[7];
  const float* beta   = (const float*)d_in[8];

  float* outE = (float*)d_out;                         // output 0: E, float32
  float* outI = outE + (size_t)BB * NRES * TOPK * NCH; // output 1: E_idx as float32

  // workspace layout
  char* p = (char*)d_ws;
  float* atoms = (float*)p;                 p += (size_t)BB * NRES * 16 * 4;   // 256 KB
  int*   eidx  = (int*)p;                   p += (size_t)BB * NRES * TOPK * 4; // 480 KB
  float* dn    = (float*)p;                 p += (size_t)BB * NRES * TOPK * 4; // 480 KB
  unsigned* wB8 = (unsigned*)p;             p += (size_t)NCH * NFEAT;          // 52 KB
  float4* Cpk  = (float4*)p;                // 64 KB

  prep_kernel<<<16 + (NFEAT * NCH / 4 + 255) / 256, 256, 0, stream>>>(X, w_edge, atoms, Cpk, wB8);
  topk_kernel<<<BB * NRES / 8, 256, 0, stream>>>(Cpk, eidx, dn, outI);
  edge_mfma_kernel<<<BB * NRES / RPB, 256, 0, stream>>>(atoms, eidx, dn, ridx, chain,
                                                        w_pos, b_pos, wB8, gamma, beta, outE);
}